// Round 1
// baseline (644.031 us; speedup 1.0000x reference)
//
#include <hip/hip_runtime.h>

// GCN 3-layer: x -> GCNConv(W1)+BN+ReLU -> GCNConv(W2)+BN+ReLU -> GCNConv(W3)
// Shared normalized adjacency (self-loops, sym norm) built once per launch as
// destination-sorted CSR; aggregation is gather-based (no float atomics).

constexpr float BN_EPS = 1e-5f;

// ---------------- graph build ----------------

__global__ void k_init(float* degf, int* counts, int n) {
    int i = blockIdx.x * blockDim.x + threadIdx.x;
    if (i < n) { degf[i] = 1.0f; counts[i] = 0; }
}

__global__ void k_deg(const int* __restrict__ col_idx, const float* __restrict__ ew,
                      float* degf, int* counts, int e_cnt) {
    int e = blockIdx.x * blockDim.x + threadIdx.x;
    if (e < e_cnt) {
        int c = col_idx[e];
        atomicAdd(&counts[c], 1);
        atomicAdd(&degf[c], ew[e]);
    }
}

__global__ void k_dis(const float* __restrict__ degf, float* dis, int n) {
    int i = blockIdx.x * blockDim.x + threadIdx.x;
    if (i < n) dis[i] = rsqrtf(degf[i]);   // deg >= 1.0 always (self-loop)
}

// two-level exclusive scan of counts -> row_ptr
__global__ void k_scan1(const int* __restrict__ counts, int* bsum, int n) {
    __shared__ int s[256];
    int i = blockIdx.x * 256 + threadIdx.x;
    s[threadIdx.x] = (i < n) ? counts[i] : 0;
    __syncthreads();
    for (int off = 128; off > 0; off >>= 1) {
        if (threadIdx.x < off) s[threadIdx.x] += s[threadIdx.x + off];
        __syncthreads();
    }
    if (threadIdx.x == 0) bsum[blockIdx.x] = s[0];
}

__global__ void k_scan2(const int* __restrict__ bsum, int* boff, int nb) {
    __shared__ int s[256];
    int t = threadIdx.x;
    int v = (t < nb) ? bsum[t] : 0;
    s[t] = v;
    __syncthreads();
    for (int off = 1; off < 256; off <<= 1) {
        int x = (t >= off) ? s[t - off] : 0;
        __syncthreads();
        s[t] += x;
        __syncthreads();
    }
    if (t < nb) boff[t] = s[t] - v;  // exclusive
}

__global__ void k_scan3(const int* __restrict__ counts, const int* __restrict__ boff,
                        int* row_ptr, int* cursor, int n, int e_total) {
    __shared__ int s[256];
    int t = threadIdx.x;
    int i = blockIdx.x * 256 + t;
    int v = (i < n) ? counts[i] : 0;
    s[t] = v;
    __syncthreads();
    for (int off = 1; off < 256; off <<= 1) {
        int x = (t >= off) ? s[t - off] : 0;
        __syncthreads();
        s[t] += x;
        __syncthreads();
    }
    int ex = s[t] - v + boff[blockIdx.x];
    if (i < n) { row_ptr[i] = ex; cursor[i] = ex; }
    if (i == 0) row_ptr[n] = e_total;
}

__global__ void k_fill(const int* __restrict__ row_idx, const int* __restrict__ col_idx,
                       const float* __restrict__ ew, const float* __restrict__ dis,
                       int* cursor, int* srcA, float* normA, int e_cnt) {
    int e = blockIdx.x * blockDim.x + threadIdx.x;
    if (e < e_cnt) {
        int r = row_idx[e];
        int c = col_idx[e];
        float nm = dis[r] * ew[e] * dis[c];
        int p = atomicAdd(&cursor[c], 1);
        srcA[p] = r;
        normA[p] = nm;
    }
}

// ---------------- dense transform: Y[n][f] = sum_k X[n][k] * W[f][k] ----------------
// 64 nodes per block, 256 threads; wave w handles features [w*FQ, (w+1)*FQ).
// W accessed at wave-uniform indices (readfirstlane) -> scalar loads, so each
// inner FMA is v_fmac with SGPR W operand + VGPR x operand.

template <int K, int F>
__global__ __launch_bounds__(256) void k_gemm(const float* __restrict__ X,
                                              const float* __restrict__ W,
                                              float* __restrict__ Y, int n) {
    constexpr int FQ = F / 4;
    constexpr int LK = K + 1;   // +1 pad: lanes (node,k) -> bank (node+k)%32, 2-way = free
    __shared__ float xs[64 * LK];
    int n0 = blockIdx.x * 64;

    // stage X tile (coalesced float4 global reads)
    for (int idx = threadIdx.x; idx < 64 * K / 4; idx += 256) {
        int el = idx * 4;
        int nn = el / K, kk = el % K;
        float4 val;
        if (n0 + nn < n) val = *(const float4*)(X + (size_t)(n0 + nn) * K + kk);
        else             val = make_float4(0.f, 0.f, 0.f, 0.f);
        xs[nn * LK + kk + 0] = val.x;
        xs[nn * LK + kk + 1] = val.y;
        xs[nn * LK + kk + 2] = val.z;
        xs[nn * LK + kk + 3] = val.w;
    }
    __syncthreads();

    int lane_n = threadIdx.x & 63;
    int fbase = __builtin_amdgcn_readfirstlane((int)(threadIdx.x >> 6)) * FQ;
    const float* __restrict__ Wp = W + (size_t)fbase * K;

    float acc[FQ];
#pragma unroll
    for (int j = 0; j < FQ; ++j) acc[j] = 0.f;

#pragma unroll 4
    for (int k = 0; k < K; ++k) {
        float xv = xs[lane_n * LK + k];
#pragma unroll
        for (int j = 0; j < FQ; ++j) acc[j] = fmaf(Wp[j * K + k], xv, acc[j]);
    }

    int nn = n0 + lane_n;
    if (nn < n) {
        float* yp = Y + (size_t)nn * F + fbase;
#pragma unroll
        for (int j = 0; j < FQ; j += 4) {
            *(float4*)(yp + j) = make_float4(acc[j], acc[j + 1], acc[j + 2], acc[j + 3]);
        }
    }
}

// ---------------- aggregation (gather over CSR) + fused epilogue ----------------
// thread = (node, feature). Self-loop term dis[n]^2 * xw[n] initializes acc.

template <int F, bool BN>
__global__ __launch_bounds__(256) void k_aggr(
    const float* __restrict__ xw, const int* __restrict__ row_ptr,
    const int* __restrict__ srcA, const float* __restrict__ normA,
    const float* __restrict__ dis, const float* __restrict__ bias,
    const float* __restrict__ g, const float* __restrict__ beta,
    const float* __restrict__ m, const float* __restrict__ v,
    float* __restrict__ out, int n) {
    int t = blockIdx.x * 256 + threadIdx.x;
    int node = t / F;
    int f = t - node * F;
    if (node >= n) return;

    float d = dis[node];
    float acc = d * d * xw[(size_t)node * F + f];   // self-loop (norm = dis^2, w=1)

    int e0 = row_ptr[node], e1 = row_ptr[node + 1];
    for (int e = e0; e < e1; ++e) {
        acc = fmaf(normA[e], xw[(size_t)srcA[e] * F + f], acc);
    }

    acc += bias[f];
    if (BN) {
        acc = (acc - m[f]) * rsqrtf(v[f] + BN_EPS) * g[f] + beta[f];
        acc = fmaxf(acc, 0.f);
    }
    out[(size_t)node * F + f] = acc;
}

// ---------------- launch ----------------

extern "C" void kernel_launch(void* const* d_in, const int* in_sizes, int n_in,
                              void* d_out, int out_size, void* d_ws, size_t ws_size,
                              hipStream_t stream) {
    constexpr int IN = 128, H = 96, OUT = 64;

    const float* x   = (const float*)d_in[0];
    const int*   ei  = (const int*)d_in[1];
    const float* ew  = (const float*)d_in[2];
    const float* W1  = (const float*)d_in[3];
    const float* b1  = (const float*)d_in[4];
    const float* W2  = (const float*)d_in[5];
    const float* b2  = (const float*)d_in[6];
    const float* W3  = (const float*)d_in[7];
    const float* b3  = (const float*)d_in[8];
    const float* g1  = (const float*)d_in[9];
    const float* be1 = (const float*)d_in[10];
    const float* m1  = (const float*)d_in[11];
    const float* v1  = (const float*)d_in[12];
    const float* g2  = (const float*)d_in[13];
    const float* be2 = (const float*)d_in[14];
    const float* m2  = (const float*)d_in[15];
    const float* v2  = (const float*)d_in[16];

    const int N = in_sizes[0] / IN;   // 50000
    const int E = in_sizes[2];        // 800000
    const int* row_idx = ei;
    const int* col_idx = ei + E;

    // workspace carve-out (256B aligned)
    char* ws = (char*)d_ws;
    size_t off = 0;
    auto alloc = [&](size_t bytes) -> void* {
        void* p = ws + off;
        off = (off + bytes + 255) & ~(size_t)255;
        return p;
    };
    float* degf   = (float*)alloc((size_t)N * 4);
    float* dis    = (float*)alloc((size_t)N * 4);
    int*   counts = (int*)alloc((size_t)N * 4);
    int*   cursor = (int*)alloc((size_t)N * 4);
    int*   row_ptr= (int*)alloc((size_t)(N + 1) * 4);
    int*   bsum   = (int*)alloc(256 * 4);
    int*   boff   = (int*)alloc(256 * 4);
    int*   srcA   = (int*)alloc((size_t)E * 4);
    float* normA  = (float*)alloc((size_t)E * 4);
    float* bufA   = (float*)alloc((size_t)N * H * 4);
    float* bufB   = (float*)alloc((size_t)N * H * 4);
    (void)ws_size; (void)n_in; (void)out_size;

    const int NB = (N + 255) / 256;   // 196 (<= 256 required by k_scan2)

    k_init<<<NB, 256, 0, stream>>>(degf, counts, N);
    k_deg<<<(E + 255) / 256, 256, 0, stream>>>(col_idx, ew, degf, counts, E);
    k_dis<<<NB, 256, 0, stream>>>(degf, dis, N);
    k_scan1<<<NB, 256, 0, stream>>>(counts, bsum, N);
    k_scan2<<<1, 256, 0, stream>>>(bsum, boff, NB);
    k_scan3<<<NB, 256, 0, stream>>>(counts, boff, row_ptr, cursor, N, E);
    k_fill<<<(E + 255) / 256, 256, 0, stream>>>(row_idx, col_idx, ew, dis, cursor,
                                                srcA, normA, E);

    const int GN = (N + 63) / 64;

    // layer 1: x[N,128] @ W1^T -> bufA[N,96]; aggregate + b1 + BN1 + ReLU -> bufB
    k_gemm<IN, H><<<GN, 256, 0, stream>>>(x, W1, bufA, N);
    k_aggr<H, true><<<((size_t)N * H + 255) / 256, 256, 0, stream>>>(
        bufA, row_ptr, srcA, normA, dis, b1, g1, be1, m1, v1, bufB, N);

    // layer 2
    k_gemm<H, H><<<GN, 256, 0, stream>>>(bufB, W2, bufA, N);
    k_aggr<H, true><<<((size_t)N * H + 255) / 256, 256, 0, stream>>>(
        bufA, row_ptr, srcA, normA, dis, b2, g2, be2, m2, v2, bufB, N);

    // layer 3: -> d_out[N,64]
    k_gemm<H, OUT><<<GN, 256, 0, stream>>>(bufB, W3, bufA, N);
    k_aggr<OUT, false><<<((size_t)N * OUT + 255) / 256, 256, 0, stream>>>(
        bufA, row_ptr, srcA, normA, dis, b3, nullptr, nullptr, nullptr, nullptr,
        (float*)d_out, N);
}

// Round 2
// 434.832 us; speedup vs baseline: 1.4811x; 1.4811x over previous
//
#include <hip/hip_runtime.h>

// GCN 3-layer: x -> GCNConv(W1)+BN+ReLU -> GCNConv(W2)+BN+ReLU -> GCNConv(W3)
// Dest-sorted CSR built once per launch (shared norm); gather aggregation with
// float4 features + 4-edge unroll for memory-level parallelism.

constexpr float BN_EPS = 1e-5f;

__device__ inline float4 f4fma(float s, float4 a, float4 b) {
    return make_float4(fmaf(s, a.x, b.x), fmaf(s, a.y, b.y),
                       fmaf(s, a.z, b.z), fmaf(s, a.w, b.w));
}

// ---------------- graph build ----------------

__global__ void k_init(float* degf, int* counts, int n) {
    int i = blockIdx.x * blockDim.x + threadIdx.x;
    if (i < n) { degf[i] = 1.0f; counts[i] = 0; }
}

__global__ void k_deg(const int* __restrict__ col_idx, const float* __restrict__ ew,
                      float* degf, int* counts, int e_cnt) {
    int e = blockIdx.x * blockDim.x + threadIdx.x;
    if (e < e_cnt) {
        int c = col_idx[e];
        atomicAdd(&counts[c], 1);
        atomicAdd(&degf[c], ew[e]);
    }
}

__global__ void k_dis(const float* __restrict__ degf, float* dis, int n) {
    int i = blockIdx.x * blockDim.x + threadIdx.x;
    if (i < n) dis[i] = rsqrtf(degf[i]);   // deg >= 1.0 always (self-loop)
}

// two-level exclusive scan of counts -> row_ptr
__global__ void k_scan1(const int* __restrict__ counts, int* bsum, int n) {
    __shared__ int s[256];
    int i = blockIdx.x * 256 + threadIdx.x;
    s[threadIdx.x] = (i < n) ? counts[i] : 0;
    __syncthreads();
    for (int off = 128; off > 0; off >>= 1) {
        if (threadIdx.x < off) s[threadIdx.x] += s[threadIdx.x + off];
        __syncthreads();
    }
    if (threadIdx.x == 0) bsum[blockIdx.x] = s[0];
}

__global__ void k_scan2(const int* __restrict__ bsum, int* boff, int nb) {
    __shared__ int s[256];
    int t = threadIdx.x;
    int v = (t < nb) ? bsum[t] : 0;
    s[t] = v;
    __syncthreads();
    for (int off = 1; off < 256; off <<= 1) {
        int x = (t >= off) ? s[t - off] : 0;
        __syncthreads();
        s[t] += x;
        __syncthreads();
    }
    if (t < nb) boff[t] = s[t] - v;  // exclusive
}

__global__ void k_scan3(const int* __restrict__ counts, const int* __restrict__ boff,
                        int* row_ptr, int* cursor, int n, int e_total) {
    __shared__ int s[256];
    int t = threadIdx.x;
    int i = blockIdx.x * 256 + t;
    int v = (i < n) ? counts[i] : 0;
    s[t] = v;
    __syncthreads();
    for (int off = 1; off < 256; off <<= 1) {
        int x = (t >= off) ? s[t - off] : 0;
        __syncthreads();
        s[t] += x;
        __syncthreads();
    }
    int ex = s[t] - v + boff[blockIdx.x];
    if (i < n) { row_ptr[i] = ex; cursor[i] = ex; }
    if (i == 0) row_ptr[n] = e_total;
}

// packed edge record: .x = src node, .y = norm (bit-cast float)
__global__ void k_fill(const int* __restrict__ row_idx, const int* __restrict__ col_idx,
                       const float* __restrict__ ew, const float* __restrict__ dis,
                       int* cursor, int2* ep, int e_cnt) {
    int e = blockIdx.x * blockDim.x + threadIdx.x;
    if (e < e_cnt) {
        int r = row_idx[e];
        int c = col_idx[e];
        float nm = dis[r] * ew[e] * dis[c];
        int p = atomicAdd(&cursor[c], 1);
        ep[p] = make_int2(r, __float_as_int(nm));
    }
}

// ---------------- dense transform: Y[n][f] = sum_k X[n][k] * W[f][k] ----------------

template <int K, int F>
__global__ __launch_bounds__(256) void k_gemm(const float* __restrict__ X,
                                              const float* __restrict__ W,
                                              float* __restrict__ Y, int n) {
    constexpr int FQ = F / 4;
    constexpr int LK = K + 1;   // +1 pad: 2-way LDS aliasing = free
    __shared__ float xs[64 * LK];
    int n0 = blockIdx.x * 64;

    for (int idx = threadIdx.x; idx < 64 * K / 4; idx += 256) {
        int el = idx * 4;
        int nn = el / K, kk = el % K;
        float4 val;
        if (n0 + nn < n) val = *(const float4*)(X + (size_t)(n0 + nn) * K + kk);
        else             val = make_float4(0.f, 0.f, 0.f, 0.f);
        xs[nn * LK + kk + 0] = val.x;
        xs[nn * LK + kk + 1] = val.y;
        xs[nn * LK + kk + 2] = val.z;
        xs[nn * LK + kk + 3] = val.w;
    }
    __syncthreads();

    int lane_n = threadIdx.x & 63;
    int fbase = __builtin_amdgcn_readfirstlane((int)(threadIdx.x >> 6)) * FQ;
    const float* __restrict__ Wp = W + (size_t)fbase * K;

    float acc[FQ];
#pragma unroll
    for (int j = 0; j < FQ; ++j) acc[j] = 0.f;

#pragma unroll 4
    for (int k = 0; k < K; ++k) {
        float xv = xs[lane_n * LK + k];
#pragma unroll
        for (int j = 0; j < FQ; ++j) acc[j] = fmaf(Wp[j * K + k], xv, acc[j]);
    }

    int nn = n0 + lane_n;
    if (nn < n) {
        float* yp = Y + (size_t)nn * F + fbase;
#pragma unroll
        for (int j = 0; j < FQ; j += 4) {
            *(float4*)(yp + j) = make_float4(acc[j], acc[j + 1], acc[j + 2], acc[j + 3]);
        }
    }
}

// ---------------- aggregation (gather over CSR) + fused epilogue ----------------
// thread = (node, float4 feature chunk); edge loop unrolled x4 for MLP.

template <int F, bool BN>
__global__ __launch_bounds__(256) void k_aggr(
    const float4* __restrict__ xw4, const int* __restrict__ row_ptr,
    const int2* __restrict__ ep,
    const float* __restrict__ dis, const float* __restrict__ bias,
    const float* __restrict__ g, const float* __restrict__ beta,
    const float* __restrict__ m, const float* __restrict__ v,
    float4* __restrict__ out4, int n) {
    constexpr int FQ = F / 4;
    int t = blockIdx.x * 256 + threadIdx.x;
    int node = t / FQ;
    int q = t - node * FQ;
    if (node >= n) return;

    float d = dis[node];
    float d2 = d * d;
    float4 self = xw4[(size_t)node * FQ + q];
    float4 acc = make_float4(d2 * self.x, d2 * self.y, d2 * self.z, d2 * self.w);

    int e0 = row_ptr[node], e1 = row_ptr[node + 1];
    int e = e0;
    for (; e + 4 <= e1; e += 4) {
        int2 p0 = ep[e + 0];
        int2 p1 = ep[e + 1];
        int2 p2 = ep[e + 2];
        int2 p3 = ep[e + 3];
        float4 x0 = xw4[(size_t)p0.x * FQ + q];
        float4 x1 = xw4[(size_t)p1.x * FQ + q];
        float4 x2 = xw4[(size_t)p2.x * FQ + q];
        float4 x3 = xw4[(size_t)p3.x * FQ + q];
        acc = f4fma(__int_as_float(p0.y), x0, acc);
        acc = f4fma(__int_as_float(p1.y), x1, acc);
        acc = f4fma(__int_as_float(p2.y), x2, acc);
        acc = f4fma(__int_as_float(p3.y), x3, acc);
    }
    for (; e < e1; ++e) {
        int2 p = ep[e];
        float4 xv = xw4[(size_t)p.x * FQ + q];
        acc = f4fma(__int_as_float(p.y), xv, acc);
    }

    int fb = q * 4;
    float4 bb = *(const float4*)(bias + fb);
    acc.x += bb.x; acc.y += bb.y; acc.z += bb.z; acc.w += bb.w;
    if (BN) {
        float4 gm = *(const float4*)(g + fb);
        float4 bt = *(const float4*)(beta + fb);
        float4 mm = *(const float4*)(m + fb);
        float4 vv = *(const float4*)(v + fb);
        acc.x = fmaxf((acc.x - mm.x) * rsqrtf(vv.x + BN_EPS) * gm.x + bt.x, 0.f);
        acc.y = fmaxf((acc.y - mm.y) * rsqrtf(vv.y + BN_EPS) * gm.y + bt.y, 0.f);
        acc.z = fmaxf((acc.z - mm.z) * rsqrtf(vv.z + BN_EPS) * gm.z + bt.z, 0.f);
        acc.w = fmaxf((acc.w - mm.w) * rsqrtf(vv.w + BN_EPS) * gm.w + bt.w, 0.f);
    }
    out4[(size_t)node * FQ + q] = acc;
}

// ---------------- launch ----------------

extern "C" void kernel_launch(void* const* d_in, const int* in_sizes, int n_in,
                              void* d_out, int out_size, void* d_ws, size_t ws_size,
                              hipStream_t stream) {
    constexpr int IN = 128, H = 96, OUT = 64;

    const float* x   = (const float*)d_in[0];
    const int*   ei  = (const int*)d_in[1];
    const float* ew  = (const float*)d_in[2];
    const float* W1  = (const float*)d_in[3];
    const float* b1  = (const float*)d_in[4];
    const float* W2  = (const float*)d_in[5];
    const float* b2  = (const float*)d_in[6];
    const float* W3  = (const float*)d_in[7];
    const float* b3  = (const float*)d_in[8];
    const float* g1  = (const float*)d_in[9];
    const float* be1 = (const float*)d_in[10];
    const float* m1  = (const float*)d_in[11];
    const float* v1  = (const float*)d_in[12];
    const float* g2  = (const float*)d_in[13];
    const float* be2 = (const float*)d_in[14];
    const float* m2  = (const float*)d_in[15];
    const float* v2  = (const float*)d_in[16];

    const int N = in_sizes[0] / IN;   // 50000
    const int E = in_sizes[2];        // 800000
    const int* row_idx = ei;
    const int* col_idx = ei + E;

    char* ws = (char*)d_ws;
    size_t off = 0;
    auto alloc = [&](size_t bytes) -> void* {
        void* p = ws + off;
        off = (off + bytes + 255) & ~(size_t)255;
        return p;
    };
    float* degf   = (float*)alloc((size_t)N * 4);
    float* dis    = (float*)alloc((size_t)N * 4);
    int*   counts = (int*)alloc((size_t)N * 4);
    int*   cursor = (int*)alloc((size_t)N * 4);
    int*   row_ptr= (int*)alloc((size_t)(N + 1) * 4);
    int*   bsum   = (int*)alloc(256 * 4);
    int*   boff   = (int*)alloc(256 * 4);
    int2*  ep     = (int2*)alloc((size_t)E * 8);
    float* bufA   = (float*)alloc((size_t)N * H * 4);
    float* bufB   = (float*)alloc((size_t)N * H * 4);
    (void)ws_size; (void)n_in; (void)out_size;

    const int NB = (N + 255) / 256;   // 196 (<= 256 required by k_scan2)

    k_init<<<NB, 256, 0, stream>>>(degf, counts, N);
    k_deg<<<(E + 255) / 256, 256, 0, stream>>>(col_idx, ew, degf, counts, E);
    k_dis<<<NB, 256, 0, stream>>>(degf, dis, N);
    k_scan1<<<NB, 256, 0, stream>>>(counts, bsum, N);
    k_scan2<<<1, 256, 0, stream>>>(bsum, boff, NB);
    k_scan3<<<NB, 256, 0, stream>>>(counts, boff, row_ptr, cursor, N, E);
    k_fill<<<(E + 255) / 256, 256, 0, stream>>>(row_idx, col_idx, ew, dis, cursor,
                                                ep, E);

    const int GN = (N + 63) / 64;

    // layer 1
    k_gemm<IN, H><<<GN, 256, 0, stream>>>(x, W1, bufA, N);
    k_aggr<H, true><<<((size_t)N * (H / 4) + 255) / 256, 256, 0, stream>>>(
        (const float4*)bufA, row_ptr, ep, dis, b1, g1, be1, m1, v1,
        (float4*)bufB, N);

    // layer 2
    k_gemm<H, H><<<GN, 256, 0, stream>>>(bufB, W2, bufA, N);
    k_aggr<H, true><<<((size_t)N * (H / 4) + 255) / 256, 256, 0, stream>>>(
        (const float4*)bufA, row_ptr, ep, dis, b2, g2, be2, m2, v2,
        (float4*)bufB, N);

    // layer 3
    k_gemm<H, OUT><<<GN, 256, 0, stream>>>(bufB, W3, bufA, N);
    k_aggr<OUT, false><<<((size_t)N * (OUT / 4) + 255) / 256, 256, 0, stream>>>(
        (const float4*)bufA, row_ptr, ep, dis, b3, nullptr, nullptr, nullptr, nullptr,
        (float4*)d_out, N);
}

// Round 3
// 370.794 us; speedup vs baseline: 1.7369x; 1.1727x over previous
//
#include <hip/hip_runtime.h>

// GCN 3-layer: x -> GCNConv(W1)+BN+ReLU -> GCNConv(W2)+BN+ReLU -> GCNConv(W3)
// Dest-sorted CSR built once per launch. ONE u64 atomic per edge packs
// {count(hi32) | fixed-point weight-sum(lo32)} and its return value gives the
// edge's rank in its destination bucket -> atomic-free CSR fill.

constexpr float BN_EPS = 1e-5f;
constexpr float FIXED_SCALE = 33554432.0f;        // 2^25
constexpr float INV_FIXED_SCALE = 1.0f / 33554432.0f;

__device__ inline float4 f4fma(float s, float4 a, float4 b) {
    return make_float4(fmaf(s, a.x, b.x), fmaf(s, a.y, b.y),
                       fmaf(s, a.z, b.z), fmaf(s, a.w, b.w));
}

// ---------------- graph build ----------------

__global__ void k_init(unsigned long long* packed, int n) {
    int i = blockIdx.x * blockDim.x + threadIdx.x;
    if (i < n) packed[i] = 0ull;
}

// one u64 atomic per edge; old>>32 = rank of this edge within its dest bucket
__global__ void k_deg(const int* __restrict__ col_idx, const float* __restrict__ ew,
                      unsigned long long* packed, int* rank, int e_cnt) {
    int e = blockIdx.x * blockDim.x + threadIdx.x;
    if (e < e_cnt) {
        int c = col_idx[e];
        unsigned int wfix = (unsigned int)(ew[e] * FIXED_SCALE + 0.5f);
        unsigned long long inc = (1ull << 32) | (unsigned long long)wfix;
        unsigned long long old = atomicAdd(&packed[c], inc);
        rank[e] = (int)(old >> 32);
    }
}

// block-sum of counts (hi32) + fused dis = rsqrt(1 + wsum) computation
__global__ void k_scan1(const unsigned long long* __restrict__ packed,
                        int* bsum, float* dis, int n) {
    __shared__ int s[256];
    int i = blockIdx.x * 256 + threadIdx.x;
    int cnt = 0;
    if (i < n) {
        unsigned long long p = packed[i];
        cnt = (int)(p >> 32);
        float wsum = (float)(unsigned int)(p & 0xffffffffull) * INV_FIXED_SCALE;
        dis[i] = rsqrtf(1.0f + wsum);   // self-loop weight 1 included
    }
    s[threadIdx.x] = cnt;
    __syncthreads();
    for (int off = 128; off > 0; off >>= 1) {
        if (threadIdx.x < off) s[threadIdx.x] += s[threadIdx.x + off];
        __syncthreads();
    }
    if (threadIdx.x == 0) bsum[blockIdx.x] = s[0];
}

__global__ void k_scan2(const int* __restrict__ bsum, int* boff, int nb) {
    __shared__ int s[256];
    int t = threadIdx.x;
    int v = (t < nb) ? bsum[t] : 0;
    s[t] = v;
    __syncthreads();
    for (int off = 1; off < 256; off <<= 1) {
        int x = (t >= off) ? s[t - off] : 0;
        __syncthreads();
        s[t] += x;
        __syncthreads();
    }
    if (t < nb) boff[t] = s[t] - v;  // exclusive
}

__global__ void k_scan3(const unsigned long long* __restrict__ packed,
                        const int* __restrict__ boff,
                        int* row_ptr, int n, int e_total) {
    __shared__ int s[256];
    int t = threadIdx.x;
    int i = blockIdx.x * 256 + t;
    int v = (i < n) ? (int)(packed[i] >> 32) : 0;
    s[t] = v;
    __syncthreads();
    for (int off = 1; off < 256; off <<= 1) {
        int x = (t >= off) ? s[t - off] : 0;
        __syncthreads();
        s[t] += x;
        __syncthreads();
    }
    int ex = s[t] - v + boff[blockIdx.x];
    if (i < n) row_ptr[i] = ex;
    if (i == 0) row_ptr[n] = e_total;
}

// atomic-free fill: slot = row_ptr[dest] + rank
__global__ void k_fill(const int* __restrict__ row_idx, const int* __restrict__ col_idx,
                       const float* __restrict__ ew, const float* __restrict__ dis,
                       const int* __restrict__ row_ptr, const int* __restrict__ rank,
                       int2* ep, int e_cnt) {
    int e = blockIdx.x * blockDim.x + threadIdx.x;
    if (e < e_cnt) {
        int r = row_idx[e];
        int c = col_idx[e];
        float nm = dis[r] * ew[e] * dis[c];
        int p = row_ptr[c] + rank[e];
        ep[p] = make_int2(r, __float_as_int(nm));
    }
}

// ---------------- dense transform: Y[n][f] = sum_k X[n][k] * W[f][k] ----------------

template <int K, int F>
__global__ __launch_bounds__(256) void k_gemm(const float* __restrict__ X,
                                              const float* __restrict__ W,
                                              float* __restrict__ Y, int n) {
    constexpr int FQ = F / 4;
    constexpr int LK = K + 1;   // +1 pad: 2-way LDS aliasing = free
    __shared__ float xs[64 * LK];
    int n0 = blockIdx.x * 64;

    for (int idx = threadIdx.x; idx < 64 * K / 4; idx += 256) {
        int el = idx * 4;
        int nn = el / K, kk = el % K;
        float4 val;
        if (n0 + nn < n) val = *(const float4*)(X + (size_t)(n0 + nn) * K + kk);
        else             val = make_float4(0.f, 0.f, 0.f, 0.f);
        xs[nn * LK + kk + 0] = val.x;
        xs[nn * LK + kk + 1] = val.y;
        xs[nn * LK + kk + 2] = val.z;
        xs[nn * LK + kk + 3] = val.w;
    }
    __syncthreads();

    int lane_n = threadIdx.x & 63;
    int fbase = __builtin_amdgcn_readfirstlane((int)(threadIdx.x >> 6)) * FQ;
    const float* __restrict__ Wp = W + (size_t)fbase * K;

    float acc[FQ];
#pragma unroll
    for (int j = 0; j < FQ; ++j) acc[j] = 0.f;

#pragma unroll 4
    for (int k = 0; k < K; ++k) {
        float xv = xs[lane_n * LK + k];
#pragma unroll
        for (int j = 0; j < FQ; ++j) acc[j] = fmaf(Wp[j * K + k], xv, acc[j]);
    }

    int nn = n0 + lane_n;
    if (nn < n) {
        float* yp = Y + (size_t)nn * F + fbase;
#pragma unroll
        for (int j = 0; j < FQ; j += 4) {
            *(float4*)(yp + j) = make_float4(acc[j], acc[j + 1], acc[j + 2], acc[j + 3]);
        }
    }
}

// ---------------- aggregation (gather over CSR) + fused epilogue ----------------
// thread = (node, float4 feature chunk); edge loop unrolled x4 for MLP.

template <int F, bool BN>
__global__ __launch_bounds__(256) void k_aggr(
    const float4* __restrict__ xw4, const int* __restrict__ row_ptr,
    const int2* __restrict__ ep,
    const float* __restrict__ dis, const float* __restrict__ bias,
    const float* __restrict__ g, const float* __restrict__ beta,
    const float* __restrict__ m, const float* __restrict__ v,
    float4* __restrict__ out4, int n) {
    constexpr int FQ = F / 4;
    int t = blockIdx.x * 256 + threadIdx.x;
    int node = t / FQ;
    int q = t - node * FQ;
    if (node >= n) return;

    float d = dis[node];
    float d2 = d * d;
    float4 self = xw4[(size_t)node * FQ + q];
    float4 acc = make_float4(d2 * self.x, d2 * self.y, d2 * self.z, d2 * self.w);

    int e0 = row_ptr[node], e1 = row_ptr[node + 1];
    int e = e0;
    for (; e + 4 <= e1; e += 4) {
        int2 p0 = ep[e + 0];
        int2 p1 = ep[e + 1];
        int2 p2 = ep[e + 2];
        int2 p3 = ep[e + 3];
        float4 x0 = xw4[(size_t)p0.x * FQ + q];
        float4 x1 = xw4[(size_t)p1.x * FQ + q];
        float4 x2 = xw4[(size_t)p2.x * FQ + q];
        float4 x3 = xw4[(size_t)p3.x * FQ + q];
        acc = f4fma(__int_as_float(p0.y), x0, acc);
        acc = f4fma(__int_as_float(p1.y), x1, acc);
        acc = f4fma(__int_as_float(p2.y), x2, acc);
        acc = f4fma(__int_as_float(p3.y), x3, acc);
    }
    for (; e < e1; ++e) {
        int2 p = ep[e];
        float4 xv = xw4[(size_t)p.x * FQ + q];
        acc = f4fma(__int_as_float(p.y), xv, acc);
    }

    int fb = q * 4;
    float4 bb = *(const float4*)(bias + fb);
    acc.x += bb.x; acc.y += bb.y; acc.z += bb.z; acc.w += bb.w;
    if (BN) {
        float4 gm = *(const float4*)(g + fb);
        float4 bt = *(const float4*)(beta + fb);
        float4 mm = *(const float4*)(m + fb);
        float4 vv = *(const float4*)(v + fb);
        acc.x = fmaxf((acc.x - mm.x) * rsqrtf(vv.x + BN_EPS) * gm.x + bt.x, 0.f);
        acc.y = fmaxf((acc.y - mm.y) * rsqrtf(vv.y + BN_EPS) * gm.y + bt.y, 0.f);
        acc.z = fmaxf((acc.z - mm.z) * rsqrtf(vv.z + BN_EPS) * gm.z + bt.z, 0.f);
        acc.w = fmaxf((acc.w - mm.w) * rsqrtf(vv.w + BN_EPS) * gm.w + bt.w, 0.f);
    }
    out4[(size_t)node * FQ + q] = acc;
}

// ---------------- launch ----------------

extern "C" void kernel_launch(void* const* d_in, const int* in_sizes, int n_in,
                              void* d_out, int out_size, void* d_ws, size_t ws_size,
                              hipStream_t stream) {
    constexpr int IN = 128, H = 96, OUT = 64;

    const float* x   = (const float*)d_in[0];
    const int*   ei  = (const int*)d_in[1];
    const float* ew  = (const float*)d_in[2];
    const float* W1  = (const float*)d_in[3];
    const float* b1  = (const float*)d_in[4];
    const float* W2  = (const float*)d_in[5];
    const float* b2  = (const float*)d_in[6];
    const float* W3  = (const float*)d_in[7];
    const float* b3  = (const float*)d_in[8];
    const float* g1  = (const float*)d_in[9];
    const float* be1 = (const float*)d_in[10];
    const float* m1  = (const float*)d_in[11];
    const float* v1  = (const float*)d_in[12];
    const float* g2  = (const float*)d_in[13];
    const float* be2 = (const float*)d_in[14];
    const float* m2  = (const float*)d_in[15];
    const float* v2  = (const float*)d_in[16];

    const int N = in_sizes[0] / IN;   // 50000
    const int E = in_sizes[2];        // 800000
    const int* row_idx = ei;
    const int* col_idx = ei + E;

    char* ws = (char*)d_ws;
    size_t off = 0;
    auto alloc = [&](size_t bytes) -> void* {
        void* p = ws + off;
        off = (off + bytes + 255) & ~(size_t)255;
        return p;
    };
    unsigned long long* packed = (unsigned long long*)alloc((size_t)N * 8);
    float* dis    = (float*)alloc((size_t)N * 4);
    int*   row_ptr= (int*)alloc((size_t)(N + 1) * 4);
    int*   bsum   = (int*)alloc(256 * 4);
    int*   boff   = (int*)alloc(256 * 4);
    int*   rank   = (int*)alloc((size_t)E * 4);
    int2*  ep     = (int2*)alloc((size_t)E * 8);
    float* bufA   = (float*)alloc((size_t)N * H * 4);
    float* bufB   = (float*)alloc((size_t)N * H * 4);
    (void)ws_size; (void)n_in; (void)out_size;

    const int NB = (N + 255) / 256;   // 196 (<= 256 required by k_scan2)

    k_init<<<NB, 256, 0, stream>>>(packed, N);
    k_deg<<<(E + 255) / 256, 256, 0, stream>>>(col_idx, ew, packed, rank, E);
    k_scan1<<<NB, 256, 0, stream>>>(packed, bsum, dis, N);
    k_scan2<<<1, 256, 0, stream>>>(bsum, boff, NB);
    k_scan3<<<NB, 256, 0, stream>>>(packed, boff, row_ptr, N, E);
    k_fill<<<(E + 255) / 256, 256, 0, stream>>>(row_idx, col_idx, ew, dis,
                                                row_ptr, rank, ep, E);

    const int GN = (N + 63) / 64;

    // layer 1
    k_gemm<IN, H><<<GN, 256, 0, stream>>>(x, W1, bufA, N);
    k_aggr<H, true><<<((size_t)N * (H / 4) + 255) / 256, 256, 0, stream>>>(
        (const float4*)bufA, row_ptr, ep, dis, b1, g1, be1, m1, v1,
        (float4*)bufB, N);

    // layer 2
    k_gemm<H, H><<<GN, 256, 0, stream>>>(bufB, W2, bufA, N);
    k_aggr<H, true><<<((size_t)N * (H / 4) + 255) / 256, 256, 0, stream>>>(
        (const float4*)bufA, row_ptr, ep, dis, b2, g2, be2, m2, v2,
        (float4*)bufB, N);

    // layer 3
    k_gemm<H, OUT><<<GN, 256, 0, stream>>>(bufB, W3, bufA, N);
    k_aggr<OUT, false><<<((size_t)N * (OUT / 4) + 255) / 256, 256, 0, stream>>>(
        (const float4*)bufA, row_ptr, ep, dis, b3, nullptr, nullptr, nullptr, nullptr,
        (float4*)d_out, N);
}

// Round 4
// 368.828 us; speedup vs baseline: 1.7462x; 1.0053x over previous
//
#include <hip/hip_runtime.h>

// GCN 3-layer: x -> GCNConv(W1)+BN+ReLU -> GCNConv(W2)+BN+ReLU -> GCNConv(W3)
// Dest-sorted CSR built once per launch. ONE u64 atomic per edge packs
// {count(hi32) | fixed-point weight-sum(lo32)}; its return value gives the
// edge's rank in its destination bucket -> atomic-free CSR fill.
// GEMM: 64-node LDS tile, 512 threads (8 waves) for latency hiding.
// Aggregation: float4 gather, 8-edge unroll for MLP.

constexpr float BN_EPS = 1e-5f;
constexpr float FIXED_SCALE = 33554432.0f;        // 2^25
constexpr float INV_FIXED_SCALE = 1.0f / 33554432.0f;

__device__ inline float4 f4fma(float s, float4 a, float4 b) {
    return make_float4(fmaf(s, a.x, b.x), fmaf(s, a.y, b.y),
                       fmaf(s, a.z, b.z), fmaf(s, a.w, b.w));
}

// ---------------- graph build ----------------

__global__ void k_init(unsigned long long* packed, int n) {
    int i = blockIdx.x * blockDim.x + threadIdx.x;
    if (i < n) packed[i] = 0ull;
}

// one u64 atomic per edge; old>>32 = rank of this edge within its dest bucket
__global__ void k_deg(const int* __restrict__ col_idx, const float* __restrict__ ew,
                      unsigned long long* packed, int* rank, int e_cnt) {
    int e = blockIdx.x * blockDim.x + threadIdx.x;
    if (e < e_cnt) {
        int c = col_idx[e];
        unsigned int wfix = (unsigned int)(ew[e] * FIXED_SCALE + 0.5f);
        unsigned long long inc = (1ull << 32) | (unsigned long long)wfix;
        unsigned long long old = atomicAdd(&packed[c], inc);
        rank[e] = (int)(old >> 32);
    }
}

// block-sum of counts (hi32) + fused dis = rsqrt(1 + wsum) computation
__global__ void k_scan1(const unsigned long long* __restrict__ packed,
                        int* bsum, float* dis, int n) {
    __shared__ int s[256];
    int i = blockIdx.x * 256 + threadIdx.x;
    int cnt = 0;
    if (i < n) {
        unsigned long long p = packed[i];
        cnt = (int)(p >> 32);
        float wsum = (float)(unsigned int)(p & 0xffffffffull) * INV_FIXED_SCALE;
        dis[i] = rsqrtf(1.0f + wsum);   // self-loop weight 1 included
    }
    s[threadIdx.x] = cnt;
    __syncthreads();
    for (int off = 128; off > 0; off >>= 1) {
        if (threadIdx.x < off) s[threadIdx.x] += s[threadIdx.x + off];
        __syncthreads();
    }
    if (threadIdx.x == 0) bsum[blockIdx.x] = s[0];
}

__global__ void k_scan2(const int* __restrict__ bsum, int* boff, int nb) {
    __shared__ int s[256];
    int t = threadIdx.x;
    int v = (t < nb) ? bsum[t] : 0;
    s[t] = v;
    __syncthreads();
    for (int off = 1; off < 256; off <<= 1) {
        int x = (t >= off) ? s[t - off] : 0;
        __syncthreads();
        s[t] += x;
        __syncthreads();
    }
    if (t < nb) boff[t] = s[t] - v;  // exclusive
}

__global__ void k_scan3(const unsigned long long* __restrict__ packed,
                        const int* __restrict__ boff,
                        int* row_ptr, int n, int e_total) {
    __shared__ int s[256];
    int t = threadIdx.x;
    int i = blockIdx.x * 256 + t;
    int v = (i < n) ? (int)(packed[i] >> 32) : 0;
    s[t] = v;
    __syncthreads();
    for (int off = 1; off < 256; off <<= 1) {
        int x = (t >= off) ? s[t - off] : 0;
        __syncthreads();
        s[t] += x;
        __syncthreads();
    }
    int ex = s[t] - v + boff[blockIdx.x];
    if (i < n) row_ptr[i] = ex;
    if (i == 0) row_ptr[n] = e_total;
}

// atomic-free fill: slot = row_ptr[dest] + rank
__global__ void k_fill(const int* __restrict__ row_idx, const int* __restrict__ col_idx,
                       const float* __restrict__ ew, const float* __restrict__ dis,
                       const int* __restrict__ row_ptr, const int* __restrict__ rank,
                       int2* ep, int e_cnt) {
    int e = blockIdx.x * blockDim.x + threadIdx.x;
    if (e < e_cnt) {
        int r = row_idx[e];
        int c = col_idx[e];
        float nm = dis[r] * ew[e] * dis[c];
        int p = row_ptr[c] + rank[e];
        ep[p] = make_int2(r, __float_as_int(nm));
    }
}

// ---------------- dense transform: Y[n][f] = sum_k X[n][k] * W[f][k] ----------------
// 64-node tile in LDS; 8 waves x (F/8) features each. 512 threads/block ->
// ~24 waves/CU resident to hide scalar-W-load + LDS latency.

template <int K, int F>
__global__ __launch_bounds__(512) void k_gemm(const float* __restrict__ X,
                                              const float* __restrict__ W,
                                              float* __restrict__ Y, int n) {
    constexpr int WAVES = 8;
    constexpr int FQ = F / WAVES;          // 12 (F=96) or 8 (F=64)
    constexpr int LK = K + 1;              // +1 pad: read aliasing 2-way = free
    __shared__ float xs[64 * LK];
    int n0 = blockIdx.x * 64;

    for (int idx = threadIdx.x; idx < 64 * K / 4; idx += 512) {
        int el = idx * 4;
        int nn = el / K, kk = el % K;
        float4 val;
        if (n0 + nn < n) val = *(const float4*)(X + (size_t)(n0 + nn) * K + kk);
        else             val = make_float4(0.f, 0.f, 0.f, 0.f);
        xs[nn * LK + kk + 0] = val.x;
        xs[nn * LK + kk + 1] = val.y;
        xs[nn * LK + kk + 2] = val.z;
        xs[nn * LK + kk + 3] = val.w;
    }
    __syncthreads();

    int lane_n = threadIdx.x & 63;
    int fbase = __builtin_amdgcn_readfirstlane((int)(threadIdx.x >> 6)) * FQ;
    const float* __restrict__ Wp = W + (size_t)fbase * K;

    float acc[FQ];
#pragma unroll
    for (int j = 0; j < FQ; ++j) acc[j] = 0.f;

#pragma unroll 4
    for (int k = 0; k < K; ++k) {
        float xv = xs[lane_n * LK + k];
#pragma unroll
        for (int j = 0; j < FQ; ++j) acc[j] = fmaf(Wp[j * K + k], xv, acc[j]);
    }

    int nn = n0 + lane_n;
    if (nn < n) {
        float* yp = Y + (size_t)nn * F + fbase;
#pragma unroll
        for (int j = 0; j < FQ; j += 4) {
            *(float4*)(yp + j) = make_float4(acc[j], acc[j + 1], acc[j + 2], acc[j + 3]);
        }
    }
}

// ---------------- aggregation (gather over CSR) + fused epilogue ----------------
// thread = (node, float4 feature chunk); edge loop unrolled x8 for MLP.

template <int F, bool BN>
__global__ __launch_bounds__(256) void k_aggr(
    const float4* __restrict__ xw4, const int* __restrict__ row_ptr,
    const int2* __restrict__ ep,
    const float* __restrict__ dis, const float* __restrict__ bias,
    const float* __restrict__ g, const float* __restrict__ beta,
    const float* __restrict__ m, const float* __restrict__ v,
    float4* __restrict__ out4, int n) {
    constexpr int FQ = F / 4;
    int t = blockIdx.x * 256 + threadIdx.x;
    int node = t / FQ;
    int q = t - node * FQ;
    if (node >= n) return;

    float d = dis[node];
    float d2 = d * d;
    float4 self = xw4[(size_t)node * FQ + q];
    float4 acc = make_float4(d2 * self.x, d2 * self.y, d2 * self.z, d2 * self.w);

    int e0 = row_ptr[node], e1 = row_ptr[node + 1];
    int e = e0;
    for (; e + 8 <= e1; e += 8) {
        int2 p0 = ep[e + 0];
        int2 p1 = ep[e + 1];
        int2 p2 = ep[e + 2];
        int2 p3 = ep[e + 3];
        int2 p4 = ep[e + 4];
        int2 p5 = ep[e + 5];
        int2 p6 = ep[e + 6];
        int2 p7 = ep[e + 7];
        float4 x0 = xw4[(size_t)p0.x * FQ + q];
        float4 x1 = xw4[(size_t)p1.x * FQ + q];
        float4 x2 = xw4[(size_t)p2.x * FQ + q];
        float4 x3 = xw4[(size_t)p3.x * FQ + q];
        float4 x4 = xw4[(size_t)p4.x * FQ + q];
        float4 x5 = xw4[(size_t)p5.x * FQ + q];
        float4 x6 = xw4[(size_t)p6.x * FQ + q];
        float4 x7 = xw4[(size_t)p7.x * FQ + q];
        acc = f4fma(__int_as_float(p0.y), x0, acc);
        acc = f4fma(__int_as_float(p1.y), x1, acc);
        acc = f4fma(__int_as_float(p2.y), x2, acc);
        acc = f4fma(__int_as_float(p3.y), x3, acc);
        acc = f4fma(__int_as_float(p4.y), x4, acc);
        acc = f4fma(__int_as_float(p5.y), x5, acc);
        acc = f4fma(__int_as_float(p6.y), x6, acc);
        acc = f4fma(__int_as_float(p7.y), x7, acc);
    }
    for (; e + 4 <= e1; e += 4) {
        int2 p0 = ep[e + 0];
        int2 p1 = ep[e + 1];
        int2 p2 = ep[e + 2];
        int2 p3 = ep[e + 3];
        float4 x0 = xw4[(size_t)p0.x * FQ + q];
        float4 x1 = xw4[(size_t)p1.x * FQ + q];
        float4 x2 = xw4[(size_t)p2.x * FQ + q];
        float4 x3 = xw4[(size_t)p3.x * FQ + q];
        acc = f4fma(__int_as_float(p0.y), x0, acc);
        acc = f4fma(__int_as_float(p1.y), x1, acc);
        acc = f4fma(__int_as_float(p2.y), x2, acc);
        acc = f4fma(__int_as_float(p3.y), x3, acc);
    }
    for (; e < e1; ++e) {
        int2 p = ep[e];
        float4 xv = xw4[(size_t)p.x * FQ + q];
        acc = f4fma(__int_as_float(p.y), xv, acc);
    }

    int fb = q * 4;
    float4 bb = *(const float4*)(bias + fb);
    acc.x += bb.x; acc.y += bb.y; acc.z += bb.z; acc.w += bb.w;
    if (BN) {
        float4 gm = *(const float4*)(g + fb);
        float4 bt = *(const float4*)(beta + fb);
        float4 mm = *(const float4*)(m + fb);
        float4 vv = *(const float4*)(v + fb);
        acc.x = fmaxf((acc.x - mm.x) * rsqrtf(vv.x + BN_EPS) * gm.x + bt.x, 0.f);
        acc.y = fmaxf((acc.y - mm.y) * rsqrtf(vv.y + BN_EPS) * gm.y + bt.y, 0.f);
        acc.z = fmaxf((acc.z - mm.z) * rsqrtf(vv.z + BN_EPS) * gm.z + bt.z, 0.f);
        acc.w = fmaxf((acc.w - mm.w) * rsqrtf(vv.w + BN_EPS) * gm.w + bt.w, 0.f);
    }
    out4[(size_t)node * FQ + q] = acc;
}

// ---------------- launch ----------------

extern "C" void kernel_launch(void* const* d_in, const int* in_sizes, int n_in,
                              void* d_out, int out_size, void* d_ws, size_t ws_size,
                              hipStream_t stream) {
    constexpr int IN = 128, H = 96, OUT = 64;

    const float* x   = (const float*)d_in[0];
    const int*   ei  = (const int*)d_in[1];
    const float* ew  = (const float*)d_in[2];
    const float* W1  = (const float*)d_in[3];
    const float* b1  = (const float*)d_in[4];
    const float* W2  = (const float*)d_in[5];
    const float* b2  = (const float*)d_in[6];
    const float* W3  = (const float*)d_in[7];
    const float* b3  = (const float*)d_in[8];
    const float* g1  = (const float*)d_in[9];
    const float* be1 = (const float*)d_in[10];
    const float* m1  = (const float*)d_in[11];
    const float* v1  = (const float*)d_in[12];
    const float* g2  = (const float*)d_in[13];
    const float* be2 = (const float*)d_in[14];
    const float* m2  = (const float*)d_in[15];
    const float* v2  = (const float*)d_in[16];

    const int N = in_sizes[0] / IN;   // 50000
    const int E = in_sizes[2];        // 800000
    const int* row_idx = ei;
    const int* col_idx = ei + E;

    char* ws = (char*)d_ws;
    size_t off = 0;
    auto alloc = [&](size_t bytes) -> void* {
        void* p = ws + off;
        off = (off + bytes + 255) & ~(size_t)255;
        return p;
    };
    unsigned long long* packed = (unsigned long long*)alloc((size_t)N * 8);
    float* dis    = (float*)alloc((size_t)N * 4);
    int*   row_ptr= (int*)alloc((size_t)(N + 1) * 4);
    int*   bsum   = (int*)alloc(256 * 4);
    int*   boff   = (int*)alloc(256 * 4);
    int*   rank   = (int*)alloc((size_t)E * 4);
    int2*  ep     = (int2*)alloc((size_t)E * 8);
    float* bufA   = (float*)alloc((size_t)N * H * 4);
    float* bufB   = (float*)alloc((size_t)N * H * 4);
    (void)ws_size; (void)n_in; (void)out_size;

    const int NB = (N + 255) / 256;   // 196 (<= 256 required by k_scan2)

    k_init<<<NB, 256, 0, stream>>>(packed, N);
    k_deg<<<(E + 255) / 256, 256, 0, stream>>>(col_idx, ew, packed, rank, E);
    k_scan1<<<NB, 256, 0, stream>>>(packed, bsum, dis, N);
    k_scan2<<<1, 256, 0, stream>>>(bsum, boff, NB);
    k_scan3<<<NB, 256, 0, stream>>>(packed, boff, row_ptr, N, E);
    k_fill<<<(E + 255) / 256, 256, 0, stream>>>(row_idx, col_idx, ew, dis,
                                                row_ptr, rank, ep, E);

    const int GN = (N + 63) / 64;

    // layer 1
    k_gemm<IN, H><<<GN, 512, 0, stream>>>(x, W1, bufA, N);
    k_aggr<H, true><<<((size_t)N * (H / 4) + 255) / 256, 256, 0, stream>>>(
        (const float4*)bufA, row_ptr, ep, dis, b1, g1, be1, m1, v1,
        (float4*)bufB, N);

    // layer 2
    k_gemm<H, H><<<GN, 512, 0, stream>>>(bufB, W2, bufA, N);
    k_aggr<H, true><<<((size_t)N * (H / 4) + 255) / 256, 256, 0, stream>>>(
        (const float4*)bufA, row_ptr, ep, dis, b2, g2, be2, m2, v2,
        (float4*)bufB, N);

    // layer 3
    k_gemm<H, OUT><<<GN, 512, 0, stream>>>(bufB, W3, bufA, N);
    k_aggr<OUT, false><<<((size_t)N * (OUT / 4) + 255) / 256, 256, 0, stream>>>(
        (const float4*)bufA, row_ptr, ep, dis, b3, nullptr, nullptr, nullptr, nullptr,
        (float4*)d_out, N);
}